// Round 8
// baseline (400.371 us; speedup 1.0000x reference)
//
#include <hip/hip_runtime.h>
#include <stdint.h>

#define M_DIM 8192
#define K_DIM 4096
#define N_DIM 4096

typedef __attribute__((ext_vector_type(4))) int i32x4;

// ---------------------------------------------------------------------------
// Pack int32 (values in [-128,127]) -> int8. (Unchanged, passing.)
// ---------------------------------------------------------------------------
__global__ __launch_bounds__(256) void pack_kernel(const int* __restrict__ src,
                                                   int8_t* __restrict__ dst,
                                                   int n4) {
  const int stride = gridDim.x * 256;
  for (int i = blockIdx.x * 256 + threadIdx.x; i < n4; i += stride) {
    int4 v = reinterpret_cast<const int4*>(src)[i];
    int p = (v.x & 0xff) | ((v.y & 0xff) << 8) |
            ((v.z & 0xff) << 16) | ((v.w & 0xff) << 24);
    reinterpret_cast<int*>(dst)[i] = p;
  }
}

__global__ void tail_kernel(float* __restrict__ out, const float* __restrict__ so) {
  out[(size_t)M_DIM * N_DIM] = so[0];
}

// ---------------------------------------------------------------------------
// 256x256 int8 GEMM, 2-phase schedule, COMPILER-SCHEDULED LDS waits.
// R8 change vs R6 (one variable): the two `s_waitcnt lgkmcnt(0)` +
// sched_barrier(0) pins before the MFMA clusters are REMOVED. ds_reads are
// plain C++ loads -> the compiler tracks ds_read->MFMA deps and emits
// fine-grained counted lgkmcnt (m97 evidence), starting MFMAs as soon as
// their fragments arrive instead of draining all 12 reads first.
// Everything else byte-identical to the passing R6 kernel:
//   prologue: STAGE(tile0, buf0); vmcnt(0); barrier;
//   loop kt:  STAGE(kt+1, buf^1); ds_read(buf); MFMA; vmcnt(0); barrier;
// One vmcnt(0)+barrier per K-tile (loads get a full tile to land).
// T2 st_16x32 swizzle both-sides; T1 bijective XCD swizzle; T5 setprio.
// ---------------------------------------------------------------------------
#define BM2 256
#define BN2 256
#define BK2 128
#define NT  (K_DIM / BK2)  // 32

#define ASM_VMCNT0 asm volatile("s_waitcnt vmcnt(0)" ::: "memory")
#define BARRIER()  asm volatile("s_barrier" ::: "memory")
#define SCHEDB()   __builtin_amdgcn_sched_barrier(0)

// Stage full K-tile KT (A 32KB + B 32KB) into buffer BUF. 8 loads/thread.
#define STAGE(KT, BUF) do { \
  _Pragma("unroll") \
  for (int c_ = 0; c_ < 4; ++c_) { \
    const int8_t* ga_ = A8 + (size_t)(arow0 + c_*64 + srow) * K_DIM + (size_t)(KT)*BK2 + scol; \
    __builtin_amdgcn_global_load_lds((const __attribute__((address_space(1))) void*)ga_, \
        (__attribute__((address_space(3))) void*)(lds + (BUF)*65536 + c_*8192 + tid*16), 16, 0, 0); \
  } \
  _Pragma("unroll") \
  for (int c_ = 0; c_ < 4; ++c_) { \
    const int8_t* gb_ = B8 + (size_t)(bcol0 + c_*64 + srow) * K_DIM + (size_t)(KT)*BK2 + scol; \
    __builtin_amdgcn_global_load_lds((const __attribute__((address_space(1))) void*)gb_, \
        (__attribute__((address_space(3))) void*)(lds + (BUF)*65536 + 32768 + c_*8192 + tid*16), 16, 0, 0); \
  } } while (0)

__global__ __launch_bounds__(512, 2) void gemm2p(
    const int8_t* __restrict__ A8, const int8_t* __restrict__ B8,
    float* __restrict__ out,
    const float* __restrict__ sx, const float* __restrict__ sw,
    const float* __restrict__ so) {
  __shared__ __align__(16) int8_t lds[131072];

  const int tid = threadIdx.x;
  const int lane = tid & 63;
  const int wid = tid >> 6;   // 0..7
  const int wr = wid >> 2;    // 0..1 -> 128-row strip of A
  const int wc = wid & 3;     // 0..3 -> 64-col strip of B
  const int lrow = lane & 15; // fragment row (A) / col (B)
  const int kq = lane >> 4;   // k-quarter within a 64-B k-slice

  // T1: XCD-aware bijective swizzle (512 blocks, 512 % 8 == 0).
  const int bid = blockIdx.x;
  const int wg = (bid & 7) * 64 + (bid >> 3);
  const int bm = wg & 31;   // consecutive wg share bn -> B panel L2 reuse
  const int bn = wg >> 5;
  const size_t arow0 = (size_t)bm * BM2;
  const size_t bcol0 = (size_t)bn * BN2;

  // Staging: thread t writes 16B at linear LDS offset c*8192 + t*16,
  // i.e. LDS row c*64 + (t>>3), physical col-slot t&7. Source col-slot is
  // pre-swizzled: logical = physical ^ (row&7), row&7 == (t>>3)&7.
  const int srow = tid >> 3;                               // 0..63
  const int scol = (((tid & 7) ^ ((tid >> 3) & 7)) << 4);  // bytes 0..112

  // ds_read: physical col16-slot = logical_slot ^ (row&7); row&7 == lrow&7.
  const int swz = (lrow & 7) << 4;
  const int pc0 = (0  + kq * 16) ^ swz;   // k-slice 0 (bytes 0..63)
  const int pc1 = (64 + kq * 16) ^ swz;   // k-slice 1 (bytes 64..127)
  const int aoff = (wr * 128 + lrow) * 128;         // A region base (row part)
  const int boff = 32768 + (wc * 64 + lrow) * 128;  // B region base

  i32x4 acc[8][4] = {};
  i32x4 af[8], bf[4];

  STAGE(0, 0);
  ASM_VMCNT0; BARRIER(); SCHEDB();

  for (int kt = 0; kt < NT; ++kt) {
    const int cb = kt & 1;
    const int8_t* abase = lds + cb * 65536 + aoff;
    const int8_t* bbase = lds + cb * 65536 + boff;
    if (kt < NT - 1) STAGE(kt + 1, cb ^ 1);

    // ---- k-slice 0: 12 ds_read_b128 + 32 MFMA (compiler-counted lgkm) ----
#pragma unroll
    for (int m = 0; m < 8; ++m) af[m] = *(const i32x4*)(abase + m * 2048 + pc0);
#pragma unroll
    for (int n = 0; n < 4; ++n) bf[n] = *(const i32x4*)(bbase + n * 2048 + pc0);
    __builtin_amdgcn_s_setprio(1);
#pragma unroll
    for (int m = 0; m < 8; ++m)
#pragma unroll
      for (int n = 0; n < 4; ++n)
        acc[m][n] = __builtin_amdgcn_mfma_i32_16x16x64_i8(af[m], bf[n], acc[m][n], 0, 0, 0);
    __builtin_amdgcn_s_setprio(0);

    // ---- k-slice 1 ----
#pragma unroll
    for (int m = 0; m < 8; ++m) af[m] = *(const i32x4*)(abase + m * 2048 + pc1);
#pragma unroll
    for (int n = 0; n < 4; ++n) bf[n] = *(const i32x4*)(bbase + n * 2048 + pc1);
    __builtin_amdgcn_s_setprio(1);
#pragma unroll
    for (int m = 0; m < 8; ++m)
#pragma unroll
      for (int n = 0; n < 4; ++n)
        acc[m][n] = __builtin_amdgcn_mfma_i32_16x16x64_i8(af[m], bf[n], acc[m][n], 0, 0, 0);
    __builtin_amdgcn_s_setprio(0);

    ASM_VMCNT0; BARRIER(); SCHEDB();  // next tile staged; buffers swap
  }

  // Epilogue: C/D layout col=lane&15, row=(lane>>4)*4+j (dtype-independent).
  const float s0 = *(volatile const float*)sx;
  const float s1 = *(volatile const float*)sw;
  const float s2 = *(volatile const float*)so;
  const float scale = s0 * s1 / s2;
#pragma unroll
  for (int m = 0; m < 8; ++m) {
#pragma unroll
    for (int n = 0; n < 4; ++n) {
#pragma unroll
      for (int j = 0; j < 4; ++j) {
        int gr = (int)arow0 + wr * 128 + m * 16 + kq * 4 + j;
        int gc = (int)bcol0 + wc * 64 + n * 16 + lrow;
        float v = rintf((float)acc[m][n][j] * scale);
        v = fminf(fmaxf(v, -128.f), 127.f);
        out[(size_t)gr * N_DIM + gc] = v;
      }
    }
  }
}

// ---------------------------------------------------------------------------
// Fallback (ws too small): proven 128x128 kernel, packs int32 in-kernel.
// ---------------------------------------------------------------------------
#define BM 128
#define BN 128
#define BK 64
__global__ __launch_bounds__(256) void gemm_direct(
    const int* __restrict__ A32, const int* __restrict__ B32,
    float* __restrict__ out,
    const float* __restrict__ sx, const float* __restrict__ sw,
    const float* __restrict__ so) {
  __shared__ int8_t As[BM * BK];
  __shared__ int8_t Bs[BN * BK];
  const int tid = threadIdx.x;
  const int lane = tid & 63;
  const int wid = tid >> 6;
  const int bid = blockIdx.x;
  const int bm = bid % (M_DIM / BM);
  const int bn = bid / (M_DIM / BM);
  const size_t arow0 = (size_t)bm * BM;
  const size_t bcol0 = (size_t)bn * BN;
  const int wrr = wid >> 1, wcc = wid & 1;
  const int lrow = lane & 15, kq = lane >> 4;
  i32x4 acc[4][4] = {};
  for (int kk = 0; kk < K_DIM; kk += BK) {
#pragma unroll
    for (int i = 0; i < 2; ++i) {
      int loff = i * 4096 + tid * 16;
      int r = loff >> 6, c = loff & 63;
      const int4* a4 = reinterpret_cast<const int4*>(A32 + (arow0 + r) * K_DIM + kk + c);
      const int4* b4 = reinterpret_cast<const int4*>(B32 + (bcol0 + r) * K_DIM + kk + c);
      int4 pa, pb;
      int4 t0 = a4[0], t1 = a4[1], t2 = a4[2], t3 = a4[3];
      pa.x = (t0.x & 0xff) | ((t0.y & 0xff) << 8) | ((t0.z & 0xff) << 16) | ((t0.w & 0xff) << 24);
      pa.y = (t1.x & 0xff) | ((t1.y & 0xff) << 8) | ((t1.z & 0xff) << 16) | ((t1.w & 0xff) << 24);
      pa.z = (t2.x & 0xff) | ((t2.y & 0xff) << 8) | ((t2.z & 0xff) << 16) | ((t2.w & 0xff) << 24);
      pa.w = (t3.x & 0xff) | ((t3.y & 0xff) << 8) | ((t3.z & 0xff) << 16) | ((t3.w & 0xff) << 24);
      t0 = b4[0]; t1 = b4[1]; t2 = b4[2]; t3 = b4[3];
      pb.x = (t0.x & 0xff) | ((t0.y & 0xff) << 8) | ((t0.z & 0xff) << 16) | ((t0.w & 0xff) << 24);
      pb.y = (t1.x & 0xff) | ((t1.y & 0xff) << 8) | ((t1.z & 0xff) << 16) | ((t1.w & 0xff) << 24);
      pb.z = (t2.x & 0xff) | ((t2.y & 0xff) << 8) | ((t2.z & 0xff) << 16) | ((t2.w & 0xff) << 24);
      pb.w = (t3.x & 0xff) | ((t3.y & 0xff) << 8) | ((t3.z & 0xff) << 16) | ((t3.w & 0xff) << 24);
      *reinterpret_cast<int4*>(As + loff) = pa;
      *reinterpret_cast<int4*>(Bs + loff) = pb;
    }
    __syncthreads();
    i32x4 afr[4], bfr[4];
#pragma unroll
    for (int m = 0; m < 4; ++m)
      afr[m] = *reinterpret_cast<const i32x4*>(As + (wrr * 64 + m * 16 + lrow) * BK + kq * 16);
#pragma unroll
    for (int n = 0; n < 4; ++n)
      bfr[n] = *reinterpret_cast<const i32x4*>(Bs + (wcc * 64 + n * 16 + lrow) * BK + kq * 16);
#pragma unroll
    for (int m = 0; m < 4; ++m)
#pragma unroll
      for (int n = 0; n < 4; ++n)
        acc[m][n] = __builtin_amdgcn_mfma_i32_16x16x64_i8(afr[m], bfr[n], acc[m][n], 0, 0, 0);
    __syncthreads();
  }
  const float scale = sx[0] * sw[0] / so[0];
#pragma unroll
  for (int m = 0; m < 4; ++m)
#pragma unroll
    for (int n = 0; n < 4; ++n)
#pragma unroll
      for (int j = 0; j < 4; ++j) {
        int gr = (int)arow0 + wrr * 64 + m * 16 + kq * 4 + j;
        int gc = (int)bcol0 + wcc * 64 + n * 16 + lrow;
        float v = rintf((float)acc[m][n][j] * scale);
        v = fminf(fmaxf(v, -128.f), 127.f);
        out[(size_t)gr * N_DIM + gc] = v;
      }
}

// ---------------------------------------------------------------------------
extern "C" void kernel_launch(void* const* d_in, const int* in_sizes, int n_in,
                              void* d_out, int out_size, void* d_ws, size_t ws_size,
                              hipStream_t stream) {
  const int* x32 = (const int*)d_in[0];
  const float* sx = (const float*)d_in[1];
  const int* w32 = (const int*)d_in[2];
  const float* sw = (const float*)d_in[3];
  const float* so = (const float*)d_in[4];
  float* out = (float*)d_out;

  tail_kernel<<<1, 1, 0, stream>>>(out, so);

  const size_t a_bytes = (size_t)M_DIM * K_DIM;
  const size_t b_bytes = (size_t)N_DIM * K_DIM;

  if (ws_size >= a_bytes + b_bytes) {
    int8_t* A8 = (int8_t*)d_ws;
    int8_t* B8 = A8 + a_bytes;
    pack_kernel<<<2048, 256, 0, stream>>>(x32, A8, (int)(a_bytes / 4));
    pack_kernel<<<2048, 256, 0, stream>>>(w32, B8, (int)(b_bytes / 4));
    const int grid = (M_DIM / BM2) * (N_DIM / BN2);  // 512
    gemm2p<<<grid, 512, 0, stream>>>(A8, B8, out, sx, sw, so);
  } else {
    const int grid = (M_DIM / BM) * (N_DIM / BN);
    gemm_direct<<<grid, 256, 0, stream>>>(x32, w32, out, sx, sw, so);
  }
}